// Round 2
// baseline (1274.706 us; speedup 1.0000x reference)
//
#include <hip/hip_runtime.h>
#include <hip/hip_bf16.h>

#define NN 50000
#define NE 800000
#define IND 64
#define DIM 128
#define KMSG 288   // 259 padded to 9*32
#define KUPD 256

typedef __attribute__((ext_vector_type(8))) short bf16x8;
typedef __attribute__((ext_vector_type(4))) float f32x4;

static __device__ __forceinline__ short f2bf(float f) {
  union { __hip_bfloat16 b; short s; } u;
  u.b = __float2bfloat16(f);
  return u.s;
}

// ---------------- embed: h = x @ W + b ; also bf16 mirror ----------------
__global__ __launch_bounds__(256) void embed_kernel(
    const float* __restrict__ x, const float* __restrict__ w,
    const float* __restrict__ b, float* __restrict__ h, short* __restrict__ hb) {
  __shared__ float ws[IND * DIM];   // 32 KB
  __shared__ float xs[8 * IND];     // 2 KB
  const int t = threadIdx.x;
  for (int i = t * 4; i < IND * DIM; i += 1024)
    *(float4*)(ws + i) = *(const float4*)(w + i);
  {
    int i = t * 4;
    if (i < 8 * IND)
      *(float4*)(xs + i) = *(const float4*)(x + (size_t)blockIdx.x * (8 * IND) + i);
  }
  __syncthreads();
  const int d = t & 127, g = t >> 7;
  const float bd = b[d];
  for (int nnod = g; nnod < 8; nnod += 2) {
    float acc = bd;
#pragma unroll
    for (int k = 0; k < IND; ++k) acc += xs[nnod * IND + k] * ws[k * DIM + d];
    const size_t n = (size_t)blockIdx.x * 8 + nnod;
    h[n * DIM + d] = acc;
    hb[n * DIM + d] = f2bf(acc);
  }
}

// ---------------- degree counts -> 1/max(cnt,1) ----------------
__global__ __launch_bounds__(256) void counts_kernel(const int* __restrict__ ei,
                                                     float* __restrict__ cnt) {
  int e = blockIdx.x * 256 + threadIdx.x;
  if (e < NE) atomicAdd(&cnt[ei[NE + e]], 1.0f);
}
__global__ __launch_bounds__(256) void rdenom_kernel(float* __restrict__ cnt) {
  int n = blockIdx.x * 256 + threadIdx.x;
  if (n < NN) cnt[n] = 1.0f / fmaxf(cnt[n], 1.0f);
}

// ---------------- weight transposes to bf16 [d][k] ----------------
__global__ __launch_bounds__(256) void wt_msg_kernel(const float* __restrict__ w,
                                                     short* __restrict__ wt) {
  int i = blockIdx.x * 256 + threadIdx.x;  // over 3*128*288
  if (i >= 3 * DIM * KMSG) return;
  int k = i % KMSG, d = (i / KMSG) % DIM, s = i / (KMSG * DIM);
  float v = (k < 259) ? w[((size_t)s * 259 + k) * DIM + d] : 0.0f;
  wt[i] = f2bf(v);
}
__global__ __launch_bounds__(256) void wt_upd_kernel(const float* __restrict__ w,
                                                     short* __restrict__ wt) {
  int i = blockIdx.x * 256 + threadIdx.x;  // over 3*128*256
  if (i >= 3 * DIM * KUPD) return;
  int k = i % KUPD, d = (i / KUPD) % DIM, s = i / (KUPD * DIM);
  wt[i] = f2bf(w[((size_t)s * KUPD + k) * DIM + d]);
}

// ---------------- message kernel ----------------
// block = 512 threads = 8 waves; each wave: 16 edges x 128 dims via MFMA 16x16x32
// A-frag: lane holds row m=lane&15, k=(lane>>4)*8+j  (contiguous 8 -> dwordx4)
// B-frag: lane holds col n=lane&15, same k           (from LDS wT)
// C: col=lane&15, row=(lane>>4)*4+reg
__global__ __launch_bounds__(512, 2) void msg_kernel(
    const short* __restrict__ hb, const float* __restrict__ pos,
    const int* __restrict__ ei, const short* __restrict__ wt,  // [128][288]
    const float* __restrict__ bias, float* __restrict__ agg) {
  __shared__ short wlds[DIM][168];  // phase A: k 0..159, phase B: k 160..287 (pad->168)
  const int t = threadIdx.x;
  const int wid = t >> 6, lane = t & 63;
  const int m = lane & 15, kg = lane >> 4;
  const int ebase = (blockIdx.x * 8 + wid) * 16;

  const int rA = ei[ebase + m];
  const int cA = ei[NE + ebase + m];
  const short* hrow = hb + (size_t)rA * DIM;
  const short* hcol = hb + (size_t)cA * DIM;

  bf16x8 a8 = (bf16x8)0;
  if (kg == 0) {
#pragma unroll
    for (int j = 0; j < 3; ++j)
      a8[j] = f2bf(pos[(size_t)rA * 3 + j] - pos[(size_t)cA * 3 + j]);
  }

  f32x4 acc[8];
#pragma unroll
  for (int i = 0; i < 8; ++i) acc[i] = (f32x4)0.0f;

  // phase A: stage k[0,160), compute chunks 0..4
  for (int i = t * 8; i < DIM * 160; i += 512 * 8) {
    int r = i / 160, c = i % 160;
    *(bf16x8*)(&wlds[r][c]) = *(const bf16x8*)(wt + (size_t)r * KMSG + c);
  }
  __syncthreads();
#pragma unroll
  for (int cc = 0; cc < 5; ++cc) {
    bf16x8 a = (cc < 4) ? *(const bf16x8*)(hrow + cc * 32 + kg * 8)
                        : *(const bf16x8*)(hcol + kg * 8);
#pragma unroll
    for (int tl = 0; tl < 8; ++tl) {
      bf16x8 bfr = *(const bf16x8*)(&wlds[tl * 16 + m][cc * 32 + kg * 8]);
      acc[tl] = __builtin_amdgcn_mfma_f32_16x16x32_bf16(a, bfr, acc[tl], 0, 0, 0);
    }
  }
  __syncthreads();
  // phase B: stage k[160,288), compute chunks 5..8
  for (int i = t * 8; i < DIM * 128; i += 512 * 8) {
    int r = i / 128, c = i % 128;
    *(bf16x8*)(&wlds[r][c]) = *(const bf16x8*)(wt + (size_t)r * KMSG + 160 + c);
  }
  __syncthreads();
#pragma unroll
  for (int cc = 5; cc < 9; ++cc) {
    bf16x8 a;
    if (cc < 8) a = *(const bf16x8*)(hcol + (cc - 4) * 32 + kg * 8);
    else        a = a8;
#pragma unroll
    for (int tl = 0; tl < 8; ++tl) {
      bf16x8 bfr = *(const bf16x8*)(&wlds[tl * 16 + m][(cc - 5) * 32 + kg * 8]);
      acc[tl] = __builtin_amdgcn_mfma_f32_16x16x32_bf16(a, bfr, acc[tl], 0, 0, 0);
    }
  }

  // epilogue: bias + exact gelu, wave-local LN over 128 dims, atomic scatter
  float s1[4] = {0.f, 0.f, 0.f, 0.f}, s2[4] = {0.f, 0.f, 0.f, 0.f};
#pragma unroll
  for (int tl = 0; tl < 8; ++tl) {
    float bd = bias[tl * 16 + m];
#pragma unroll
    for (int j = 0; j < 4; ++j) {
      float xv = acc[tl][j] + bd;
      float gv = 0.5f * xv * (1.0f + erff(xv * 0.70710678118654752f));
      acc[tl][j] = gv;
      s1[j] += gv;
      s2[j] += gv * gv;
    }
  }
#pragma unroll
  for (int mask = 1; mask < 16; mask <<= 1) {
#pragma unroll
    for (int j = 0; j < 4; ++j) {
      s1[j] += __shfl_xor(s1[j], mask, 64);
      s2[j] += __shfl_xor(s2[j], mask, 64);
    }
  }
#pragma unroll
  for (int j = 0; j < 4; ++j) {
    float mean = s1[j] * (1.0f / 128.0f);
    float var = s2[j] * (1.0f / 128.0f) - mean * mean;
    float rstd = rsqrtf(var + 1e-5f);
    int e = ebase + kg * 4 + j;
    int cd = ei[NE + e];
    float* dst = agg + (size_t)cd * DIM + m;
#pragma unroll
    for (int tl = 0; tl < 8; ++tl)
      atomicAdd(dst + tl * 16, (acc[tl][j] - mean) * rstd);
  }
}

// ---------------- update kernel ----------------
// ui = [h, agg/denom]; h += LN(ui @ W + b); writes f32 h and bf16 mirror
__global__ __launch_bounds__(512, 2) void upd_kernel(
    const short* __restrict__ hb, const float* __restrict__ agg,
    const float* __restrict__ rden, const short* __restrict__ wt,  // [128][256]
    const float* __restrict__ bias, float* __restrict__ h, short* __restrict__ hbo) {
  __shared__ short wlds[DIM][136];  // 4 chunks per phase, pad 128->136
  const int t = threadIdx.x;
  const int wid = t >> 6, lane = t & 63;
  const int m = lane & 15, kg = lane >> 4;
  const int nbase = (blockIdx.x * 8 + wid) * 16;
  const bool active = nbase < NN;
  const int nA = active ? (nbase + m) : 0;
  const short* hrow = hb + (size_t)nA * DIM;
  const float rd = rden[nA];

  f32x4 acc[8];
#pragma unroll
  for (int i = 0; i < 8; ++i) acc[i] = (f32x4)0.0f;

  // phase A: k[0,128) from h
  for (int i = t * 8; i < DIM * 128; i += 512 * 8) {
    int r = i / 128, c = i % 128;
    *(bf16x8*)(&wlds[r][c]) = *(const bf16x8*)(wt + (size_t)r * KUPD + c);
  }
  __syncthreads();
  if (active) {
#pragma unroll
    for (int cc = 0; cc < 4; ++cc) {
      bf16x8 a = *(const bf16x8*)(hrow + cc * 32 + kg * 8);
#pragma unroll
      for (int tl = 0; tl < 8; ++tl) {
        bf16x8 bfr = *(const bf16x8*)(&wlds[tl * 16 + m][cc * 32 + kg * 8]);
        acc[tl] = __builtin_amdgcn_mfma_f32_16x16x32_bf16(a, bfr, acc[tl], 0, 0, 0);
      }
    }
  }
  __syncthreads();
  // phase B: k[128,256) from agg/denom
  for (int i = t * 8; i < DIM * 128; i += 512 * 8) {
    int r = i / 128, c = i % 128;
    *(bf16x8*)(&wlds[r][c]) = *(const bf16x8*)(wt + (size_t)r * KUPD + 128 + c);
  }
  __syncthreads();
  if (active) {
#pragma unroll
    for (int cc = 0; cc < 4; ++cc) {
      const float* ap = agg + (size_t)nA * DIM + cc * 32 + kg * 8;
      bf16x8 a;
#pragma unroll
      for (int j = 0; j < 8; ++j) a[j] = f2bf(ap[j] * rd);
#pragma unroll
      for (int tl = 0; tl < 8; ++tl) {
        bf16x8 bfr = *(const bf16x8*)(&wlds[tl * 16 + m][cc * 32 + kg * 8]);
        acc[tl] = __builtin_amdgcn_mfma_f32_16x16x32_bf16(a, bfr, acc[tl], 0, 0, 0);
      }
    }
  }
  if (!active) return;

  // epilogue: bias, LN, residual
  float s1[4] = {0.f, 0.f, 0.f, 0.f}, s2[4] = {0.f, 0.f, 0.f, 0.f};
#pragma unroll
  for (int tl = 0; tl < 8; ++tl) {
    float bd = bias[tl * 16 + m];
#pragma unroll
    for (int j = 0; j < 4; ++j) {
      float xv = acc[tl][j] + bd;
      acc[tl][j] = xv;
      s1[j] += xv;
      s2[j] += xv * xv;
    }
  }
#pragma unroll
  for (int mask = 1; mask < 16; mask <<= 1) {
#pragma unroll
    for (int j = 0; j < 4; ++j) {
      s1[j] += __shfl_xor(s1[j], mask, 64);
      s2[j] += __shfl_xor(s2[j], mask, 64);
    }
  }
#pragma unroll
  for (int j = 0; j < 4; ++j) {
    float mean = s1[j] * (1.0f / 128.0f);
    float var = s2[j] * (1.0f / 128.0f) - mean * mean;
    float rstd = rsqrtf(var + 1e-5f);
    int n = nbase + kg * 4 + j;
#pragma unroll
    for (int tl = 0; tl < 8; ++tl) {
      int d = tl * 16 + m;
      float hv = h[(size_t)n * DIM + d] + (acc[tl][j] - mean) * rstd;
      h[(size_t)n * DIM + d] = hv;
      hbo[(size_t)n * DIM + d] = f2bf(hv);
    }
  }
}

extern "C" void kernel_launch(void* const* d_in, const int* in_sizes, int n_in,
                              void* d_out, int out_size, void* d_ws, size_t ws_size,
                              hipStream_t stream) {
  const float* x       = (const float*)d_in[0];
  const float* pos     = (const float*)d_in[1];
  const int* ei        = (const int*)d_in[2];
  const float* embed_w = (const float*)d_in[3];
  const float* embed_b = (const float*)d_in[4];
  const float* msg_w   = (const float*)d_in[5];
  const float* msg_b   = (const float*)d_in[6];
  const float* upd_w   = (const float*)d_in[7];
  const float* upd_b   = (const float*)d_in[8];
  float* h = (float*)d_out;

  char* ws = (char*)d_ws;
  size_t off = 0;
  short* hb = (short*)(ws + off);    off += (size_t)NN * DIM * 2;      // 12.8 MB
  float* agg = (float*)(ws + off);   off += (size_t)NN * DIM * 4;      // 25.6 MB
  float* rden = (float*)(ws + off);  off += (size_t)NN * 4;            // 0.2 MB
  short* wtm = (short*)(ws + off);   off += (size_t)3 * DIM * KMSG * 2;
  short* wtu = (short*)(ws + off);   off += (size_t)3 * DIM * KUPD * 2;

  hipMemsetAsync(rden, 0, (size_t)NN * 4, stream);
  counts_kernel<<<(NE + 255) / 256, 256, 0, stream>>>(ei, rden);
  rdenom_kernel<<<(NN + 255) / 256, 256, 0, stream>>>(rden);
  wt_msg_kernel<<<(3 * DIM * KMSG + 255) / 256, 256, 0, stream>>>(msg_w, wtm);
  wt_upd_kernel<<<(3 * DIM * KUPD + 255) / 256, 256, 0, stream>>>(upd_w, wtu);
  embed_kernel<<<NN / 8, 256, 0, stream>>>(x, embed_w, embed_b, h, hb);

  for (int s = 0; s < 3; ++s) {
    hipMemsetAsync(agg, 0, (size_t)NN * DIM * 4, stream);
    msg_kernel<<<NE / 128, 512, 0, stream>>>(hb, pos, ei, wtm + (size_t)s * DIM * KMSG,
                                             msg_b + s * DIM, agg);
    upd_kernel<<<(NN / 16 + 7) / 8, 512, 0, stream>>>(hb, agg, rden,
                                                      wtu + (size_t)s * DIM * KUPD,
                                                      upd_b + s * DIM, h, hb);
  }
}

// Round 3
// 879.836 us; speedup vs baseline: 1.4488x; 1.4488x over previous
//
#include <hip/hip_runtime.h>
#include <hip/hip_bf16.h>

#define NN 50000
#define NE 800000
#define IND 64
#define DIM 128
#define KUPD 256

typedef __attribute__((ext_vector_type(8))) short bf16x8;
typedef __attribute__((ext_vector_type(4))) short bf16x4;
typedef __attribute__((ext_vector_type(4))) float f32x4;

static __device__ __forceinline__ short f2bf(float f) {
  union { __hip_bfloat16 b; short s; } u;
  u.b = __float2bfloat16(f);
  return u.s;
}
static __device__ __forceinline__ float bf2f(unsigned short u) {
  union { float f; unsigned int i; } x; x.i = ((unsigned int)u) << 16; return x.f;
}

// ---------------- embed: h = x @ W + b ; also bf16 mirror ----------------
__global__ __launch_bounds__(256) void embed_kernel(
    const float* __restrict__ x, const float* __restrict__ w,
    const float* __restrict__ b, float* __restrict__ h, short* __restrict__ hb) {
  __shared__ float ws[IND * DIM];   // 32 KB
  __shared__ float xs[8 * IND];     // 2 KB
  const int t = threadIdx.x;
  for (int i = t * 4; i < IND * DIM; i += 1024)
    *(float4*)(ws + i) = *(const float4*)(w + i);
  {
    int i = t * 4;
    if (i < 8 * IND)
      *(float4*)(xs + i) = *(const float4*)(x + (size_t)blockIdx.x * (8 * IND) + i);
  }
  __syncthreads();
  const int d = t & 127, g = t >> 7;
  const float bd = b[d];
  for (int nnod = g; nnod < 8; nnod += 2) {
    float acc = bd;
#pragma unroll
    for (int k = 0; k < IND; ++k) acc += xs[nnod * IND + k] * ws[k * DIM + d];
    const size_t n = (size_t)blockIdx.x * 8 + nnod;
    h[n * DIM + d] = acc;
    hb[n * DIM + d] = f2bf(acc);
  }
}

// ---------------- degree counts (int) ----------------
__global__ __launch_bounds__(256) void counts_kernel(const int* __restrict__ ei,
                                                     int* __restrict__ cnt) {
  int e = blockIdx.x * 256 + threadIdx.x;
  if (e < NE) atomicAdd(&cnt[ei[NE + e]], 1);
}

// ---------------- single-block scan: offsets, cursor, rden ----------------
__global__ __launch_bounds__(1024) void scan_kernel(const int* __restrict__ cnt,
                                                    int* __restrict__ off,
                                                    int* __restrict__ cursor,
                                                    float* __restrict__ rden) {
  __shared__ int part[1024];
  const int t = threadIdx.x;
  const int base = t * 49;  // 1024*49 = 50176 >= NN
  int s = 0;
  for (int i = 0; i < 49; ++i) {
    int idx = base + i;
    s += (idx < NN) ? cnt[idx] : 0;
  }
  part[t] = s;
  __syncthreads();
  for (int d = 1; d < 1024; d <<= 1) {
    int v = (t >= d) ? part[t - d] : 0;
    __syncthreads();
    part[t] += v;
    __syncthreads();
  }
  int run = (t > 0) ? part[t - 1] : 0;
  for (int i = 0; i < 49; ++i) {
    int idx = base + i;
    if (idx < NN) {
      int c = cnt[idx];
      off[idx] = run;
      cursor[idx] = run;
      rden[idx] = 1.0f / fmaxf((float)c, 1.0f);
      run += c;
    }
  }
  if (t == 1023) off[NN] = run;
}

// ---------------- scatter edges into CSR buckets ----------------
__global__ __launch_bounds__(256) void scatter_kernel(const int* __restrict__ ei,
                                                      int* __restrict__ cursor,
                                                      int* __restrict__ rowOf) {
  int e = blockIdx.x * 256 + threadIdx.x;
  if (e < NE) {
    int c = ei[NE + e];
    int p = atomicAdd(&cursor[c], 1);
    rowOf[p] = ei[e];
  }
}

// ---------------- weight transposes ----------------
// wt12[s][o][k]: o<128: W1[k][o]=msg_w[s][k][o]; o>=128: W2[k][o-128]=msg_w[s][128+k][o-128]
__global__ __launch_bounds__(256) void wt12_kernel(const float* __restrict__ w,
                                                   short* __restrict__ wt) {
  int i = blockIdx.x * 256 + threadIdx.x;  // over 3*256*128
  if (i >= 3 * 256 * DIM) return;
  int k = i % DIM, o = (i / DIM) % 256, s = i / (DIM * 256);
  int krow = (o < DIM) ? k : (DIM + k);
  int d = o & (DIM - 1);
  wt[i] = f2bf(w[((size_t)s * 259 + krow) * DIM + d]);
}
__global__ __launch_bounds__(256) void wt_upd_kernel(const float* __restrict__ w,
                                                     short* __restrict__ wt) {
  int i = blockIdx.x * 256 + threadIdx.x;  // over 3*128*256
  if (i >= 3 * DIM * KUPD) return;
  int k = i % KUPD, d = (i / KUPD) % DIM, s = i / (KUPD * DIM);
  wt[i] = f2bf(w[((size_t)s * KUPD + k) * DIM + d]);
}

// ---------------- P1/P2 GEMM: P12b[n][half*128+o] = (hb @ W_half)[n][o] ----------------
// MFMA with A = weights (rows = outs), B = h nodes (cols): C col=node, row=out (j gives
// 4 consecutive outs -> 8B packed bf16 store)
__global__ __launch_bounds__(512) void p12_kernel(const short* __restrict__ hb,
                                                  const short* __restrict__ wt12_s,  // [256][128]
                                                  short* __restrict__ P12b) {
  __shared__ short wlds[DIM][136];
  const int t = threadIdx.x;
  const int wid = t >> 6, lane = t & 63;
  const int m = lane & 15, kg = lane >> 4;
  const int half = blockIdx.y;
  const int nbase = (blockIdx.x * 8 + wid) * 16;
  for (int i = t * 8; i < DIM * DIM; i += 512 * 8) {
    int r = i / DIM, c = i % DIM;
    *(bf16x8*)(&wlds[r][c]) = *(const bf16x8*)(wt12_s + ((size_t)(half * DIM + r)) * DIM + c);
  }
  __syncthreads();
  if (nbase >= NN) return;
  const short* hrow = hb + (size_t)(nbase + m) * DIM;
  f32x4 acc[8];
#pragma unroll
  for (int i = 0; i < 8; ++i) acc[i] = (f32x4)0.0f;
#pragma unroll
  for (int cc = 0; cc < 4; ++cc) {
    bf16x8 bfrag = *(const bf16x8*)(hrow + cc * 32 + kg * 8);
#pragma unroll
    for (int tl = 0; tl < 8; ++tl) {
      bf16x8 afrag = *(const bf16x8*)(&wlds[tl * 16 + m][cc * 32 + kg * 8]);
      acc[tl] = __builtin_amdgcn_mfma_f32_16x16x32_bf16(afrag, bfrag, acc[tl], 0, 0, 0);
    }
  }
#pragma unroll
  for (int tl = 0; tl < 8; ++tl) {
    bf16x4 p;
#pragma unroll
    for (int j = 0; j < 4; ++j) p[j] = f2bf(acc[tl][j]);
    *(bf16x4*)(P12b + (size_t)(nbase + m) * 256 + half * DIM + tl * 16 + kg * 4) = p;
  }
}

// ---------------- message + aggregate: one wave per destination node ----------------
__global__ __launch_bounds__(512) void msg_agg_kernel(
    const short* __restrict__ P12b, const float* __restrict__ pos,
    const int* __restrict__ rowOf, const int* __restrict__ off,
    const float* __restrict__ wmsg_s,  // msg_w + s*259*128 (f32)
    const float* __restrict__ bias_s, float* __restrict__ agg) {
  const int t = threadIdx.x;
  const int wid = t >> 6, lane = t & 63;
  const int n = blockIdx.x * 8 + wid;  // grid covers exactly NN
  const int d0 = lane * 2;
  const float w30a = wmsg_s[256 * DIM + d0], w30b = wmsg_s[256 * DIM + d0 + 1];
  const float w31a = wmsg_s[257 * DIM + d0], w31b = wmsg_s[257 * DIM + d0 + 1];
  const float w32a = wmsg_s[258 * DIM + d0], w32b = wmsg_s[258 * DIM + d0 + 1];
  const float ba = bias_s[d0], bb = bias_s[d0 + 1];
  const unsigned int u2 = *(const unsigned int*)(P12b + (size_t)n * 256 + DIM + d0);
  const float p2a = bf2f((unsigned short)(u2 & 0xffff));
  const float p2b = bf2f((unsigned short)(u2 >> 16));
  const float pc0 = pos[3 * n], pc1 = pos[3 * n + 1], pc2 = pos[3 * n + 2];
  const int start = off[n], end = off[n + 1];
  float acc0 = 0.f, acc1 = 0.f;
  for (int base = start; base < end; base += 64) {
    int mcnt = end - base;
    if (mcnt > 64) mcnt = 64;
    int r_l = (lane < mcnt) ? rowOf[base + lane] : 0;
    for (int j = 0; j < mcnt; ++j) {
      int row = __shfl(r_l, j, 64);
      unsigned int p1 = *(const unsigned int*)(P12b + (size_t)row * 256 + d0);
      float pr0 = pos[3 * row], pr1 = pos[3 * row + 1], pr2 = pos[3 * row + 2];
      float e0 = pr0 - pc0, e1 = pr1 - pc1, e2 = pr2 - pc2;
      float v0 = bf2f((unsigned short)(p1 & 0xffff)) + p2a + e0 * w30a + e1 * w31a + e2 * w32a + ba;
      float v1 = bf2f((unsigned short)(p1 >> 16)) + p2b + e0 * w30b + e1 * w31b + e2 * w32b + bb;
      float g0 = 0.5f * v0 * (1.0f + erff(v0 * 0.70710678118654752f));
      float g1 = 0.5f * v1 * (1.0f + erff(v1 * 0.70710678118654752f));
      float s1 = g0 + g1, s2 = g0 * g0 + g1 * g1;
#pragma unroll
      for (int mask = 1; mask < 64; mask <<= 1) {
        s1 += __shfl_xor(s1, mask, 64);
        s2 += __shfl_xor(s2, mask, 64);
      }
      float mean = s1 * (1.0f / 128.0f);
      float rstd = rsqrtf(s2 * (1.0f / 128.0f) - mean * mean + 1e-5f);
      acc0 += (g0 - mean) * rstd;
      acc1 += (g1 - mean) * rstd;
    }
  }
  *(float2*)(agg + (size_t)n * DIM + d0) = make_float2(acc0, acc1);
}

// ---------------- update kernel ----------------
__global__ __launch_bounds__(512, 2) void upd_kernel(
    const short* __restrict__ hb, const float* __restrict__ agg,
    const float* __restrict__ rden, const short* __restrict__ wt,  // [128][256]
    const float* __restrict__ bias, float* __restrict__ h, short* __restrict__ hbo) {
  __shared__ short wlds[DIM][136];
  const int t = threadIdx.x;
  const int wid = t >> 6, lane = t & 63;
  const int m = lane & 15, kg = lane >> 4;
  const int nbase = (blockIdx.x * 8 + wid) * 16;
  const bool active = nbase < NN;
  const int nA = active ? (nbase + m) : 0;
  const short* hrow = hb + (size_t)nA * DIM;
  const float rd = rden[nA];

  f32x4 acc[8];
#pragma unroll
  for (int i = 0; i < 8; ++i) acc[i] = (f32x4)0.0f;

  for (int i = t * 8; i < DIM * 128; i += 512 * 8) {
    int r = i / 128, c = i % 128;
    *(bf16x8*)(&wlds[r][c]) = *(const bf16x8*)(wt + (size_t)r * KUPD + c);
  }
  __syncthreads();
  if (active) {
#pragma unroll
    for (int cc = 0; cc < 4; ++cc) {
      bf16x8 a = *(const bf16x8*)(hrow + cc * 32 + kg * 8);
#pragma unroll
      for (int tl = 0; tl < 8; ++tl) {
        bf16x8 bfr = *(const bf16x8*)(&wlds[tl * 16 + m][cc * 32 + kg * 8]);
        acc[tl] = __builtin_amdgcn_mfma_f32_16x16x32_bf16(a, bfr, acc[tl], 0, 0, 0);
      }
    }
  }
  __syncthreads();
  for (int i = t * 8; i < DIM * 128; i += 512 * 8) {
    int r = i / 128, c = i % 128;
    *(bf16x8*)(&wlds[r][c]) = *(const bf16x8*)(wt + (size_t)r * KUPD + 128 + c);
  }
  __syncthreads();
  if (active) {
#pragma unroll
    for (int cc = 0; cc < 4; ++cc) {
      const float* ap = agg + (size_t)nA * DIM + cc * 32 + kg * 8;
      bf16x8 a;
#pragma unroll
      for (int j = 0; j < 8; ++j) a[j] = f2bf(ap[j] * rd);
#pragma unroll
      for (int tl = 0; tl < 8; ++tl) {
        bf16x8 bfr = *(const bf16x8*)(&wlds[tl * 16 + m][cc * 32 + kg * 8]);
        acc[tl] = __builtin_amdgcn_mfma_f32_16x16x32_bf16(a, bfr, acc[tl], 0, 0, 0);
      }
    }
  }
  if (!active) return;

  float s1[4] = {0.f, 0.f, 0.f, 0.f}, s2[4] = {0.f, 0.f, 0.f, 0.f};
#pragma unroll
  for (int tl = 0; tl < 8; ++tl) {
    float bd = bias[tl * 16 + m];
#pragma unroll
    for (int j = 0; j < 4; ++j) {
      float xv = acc[tl][j] + bd;
      acc[tl][j] = xv;
      s1[j] += xv;
      s2[j] += xv * xv;
    }
  }
#pragma unroll
  for (int mask = 1; mask < 16; mask <<= 1) {
#pragma unroll
    for (int j = 0; j < 4; ++j) {
      s1[j] += __shfl_xor(s1[j], mask, 64);
      s2[j] += __shfl_xor(s2[j], mask, 64);
    }
  }
#pragma unroll
  for (int j = 0; j < 4; ++j) {
    float mean = s1[j] * (1.0f / 128.0f);
    float var = s2[j] * (1.0f / 128.0f) - mean * mean;
    float rstd = rsqrtf(var + 1e-5f);
    int n = nbase + kg * 4 + j;
#pragma unroll
    for (int tl = 0; tl < 8; ++tl) {
      int d = tl * 16 + m;
      float hv = h[(size_t)n * DIM + d] + (acc[tl][j] - mean) * rstd;
      h[(size_t)n * DIM + d] = hv;
      hbo[(size_t)n * DIM + d] = f2bf(hv);
    }
  }
}

extern "C" void kernel_launch(void* const* d_in, const int* in_sizes, int n_in,
                              void* d_out, int out_size, void* d_ws, size_t ws_size,
                              hipStream_t stream) {
  const float* x       = (const float*)d_in[0];
  const float* pos     = (const float*)d_in[1];
  const int* ei        = (const int*)d_in[2];
  const float* embed_w = (const float*)d_in[3];
  const float* embed_b = (const float*)d_in[4];
  const float* msg_w   = (const float*)d_in[5];
  const float* msg_b   = (const float*)d_in[6];
  const float* upd_w   = (const float*)d_in[7];
  const float* upd_b   = (const float*)d_in[8];
  float* h = (float*)d_out;

  char* ws = (char*)d_ws;
  size_t off_b = 0;
  short* hb    = (short*)(ws + off_b); off_b += (size_t)NN * DIM * 2;        // 12.8 MB
  short* P12b  = (short*)(ws + off_b); off_b += (size_t)NN * 256 * 2;        // 25.6 MB
  float* agg   = (float*)(ws + off_b); off_b += (size_t)NN * DIM * 4;        // 25.6 MB
  float* rden  = (float*)(ws + off_b); off_b += (size_t)NN * 4;
  int*   cnt   = (int*)(ws + off_b);   off_b += (size_t)NN * 4;
  int*   offs  = (int*)(ws + off_b);   off_b += (size_t)(NN + 16) * 4;
  int*   cursor= (int*)(ws + off_b);   off_b += (size_t)NN * 4;
  int*   rowOf = (int*)(ws + off_b);   off_b += (size_t)NE * 4;              // 3.2 MB
  short* wt12  = (short*)(ws + off_b); off_b += (size_t)3 * 256 * DIM * 2;
  short* wtu   = (short*)(ws + off_b); off_b += (size_t)3 * DIM * KUPD * 2;

  hipMemsetAsync(cnt, 0, (size_t)NN * 4, stream);
  counts_kernel<<<(NE + 255) / 256, 256, 0, stream>>>(ei, cnt);
  scan_kernel<<<1, 1024, 0, stream>>>(cnt, offs, cursor, rden);
  scatter_kernel<<<(NE + 255) / 256, 256, 0, stream>>>(ei, cursor, rowOf);
  wt12_kernel<<<(3 * 256 * DIM + 255) / 256, 256, 0, stream>>>(msg_w, wt12);
  wt_upd_kernel<<<(3 * DIM * KUPD + 255) / 256, 256, 0, stream>>>(upd_w, wtu);
  embed_kernel<<<NN / 8, 256, 0, stream>>>(x, embed_w, embed_b, h, hb);

  for (int s = 0; s < 3; ++s) {
    p12_kernel<<<dim3((NN / 16 + 7) / 8, 2), 512, 0, stream>>>(
        hb, wt12 + (size_t)s * 256 * DIM, P12b);
    msg_agg_kernel<<<NN / 8, 512, 0, stream>>>(P12b, pos, rowOf, offs,
                                               msg_w + (size_t)s * 259 * DIM,
                                               msg_b + (size_t)s * DIM, agg);
    upd_kernel<<<(NN / 16 + 7) / 8, 512, 0, stream>>>(hb, agg, rden,
                                                      wtu + (size_t)s * DIM * KUPD,
                                                      upd_b + (size_t)s * DIM, h, hb);
  }
}

// Round 4
// 738.316 us; speedup vs baseline: 1.7265x; 1.1917x over previous
//
#include <hip/hip_runtime.h>
#include <hip/hip_bf16.h>

#define NN 50000
#define NE 800000
#define IND 64
#define DIM 128
#define KUPD 256

typedef __attribute__((ext_vector_type(8))) short bf16x8;
typedef __attribute__((ext_vector_type(4))) short bf16x4;
typedef __attribute__((ext_vector_type(4))) float f32x4;

static __device__ __forceinline__ short f2bf(float f) {
  union { __hip_bfloat16 b; short s; } u;
  u.b = __float2bfloat16(f);
  return u.s;
}
static __device__ __forceinline__ float bf2f(unsigned short u) {
  union { float f; unsigned int i; } x; x.i = ((unsigned int)u) << 16; return x.f;
}
// tanh-form gelu: x * sigmoid(1.59576912*x*(1+0.044715*x^2)); max err ~3e-3
static __device__ __forceinline__ float fgelu(float x) {
  float u = x * x;
  float z = x * (1.59576912f + 0.0713548163f * u);
  float t = __expf(-z);
  return x / (1.0f + t);
}

// ---------------- embed: h = x @ W + b ; also bf16 mirror ----------------
__global__ __launch_bounds__(256) void embed_kernel(
    const float* __restrict__ x, const float* __restrict__ w,
    const float* __restrict__ b, float* __restrict__ h, short* __restrict__ hb) {
  __shared__ float ws[IND * DIM];   // 32 KB
  __shared__ float xs[8 * IND];     // 2 KB
  const int t = threadIdx.x;
  for (int i = t * 4; i < IND * DIM; i += 1024)
    *(float4*)(ws + i) = *(const float4*)(w + i);
  {
    int i = t * 4;
    if (i < 8 * IND)
      *(float4*)(xs + i) = *(const float4*)(x + (size_t)blockIdx.x * (8 * IND) + i);
  }
  __syncthreads();
  const int d = t & 127, g = t >> 7;
  const float bd = b[d];
  for (int nnod = g; nnod < 8; nnod += 2) {
    float acc = bd;
#pragma unroll
    for (int k = 0; k < IND; ++k) acc += xs[nnod * IND + k] * ws[k * DIM + d];
    const size_t n = (size_t)blockIdx.x * 8 + nnod;
    h[n * DIM + d] = acc;
    hb[n * DIM + d] = f2bf(acc);
  }
}

// ---------------- degree counts (int) ----------------
__global__ __launch_bounds__(256) void counts_kernel(const int* __restrict__ ei,
                                                     int* __restrict__ cnt) {
  int e = blockIdx.x * 256 + threadIdx.x;
  if (e < NE) atomicAdd(&cnt[ei[NE + e]], 1);
}

// ---------------- single-block scan: offsets, cursor, rden ----------------
__global__ __launch_bounds__(1024) void scan_kernel(const int* __restrict__ cnt,
                                                    int* __restrict__ off,
                                                    int* __restrict__ cursor,
                                                    float* __restrict__ rden) {
  __shared__ int part[1024];
  const int t = threadIdx.x;
  const int base = t * 49;  // 1024*49 = 50176 >= NN
  int s = 0;
  for (int i = 0; i < 49; ++i) {
    int idx = base + i;
    s += (idx < NN) ? cnt[idx] : 0;
  }
  part[t] = s;
  __syncthreads();
  for (int d = 1; d < 1024; d <<= 1) {
    int v = (t >= d) ? part[t - d] : 0;
    __syncthreads();
    part[t] += v;
    __syncthreads();
  }
  int run = (t > 0) ? part[t - 1] : 0;
  for (int i = 0; i < 49; ++i) {
    int idx = base + i;
    if (idx < NN) {
      int c = cnt[idx];
      off[idx] = run;
      cursor[idx] = run;
      rden[idx] = 1.0f / fmaxf((float)c, 1.0f);
      run += c;
    }
  }
  if (t == 1023) off[NN] = run;
}

// ---------------- scatter edges into CSR buckets ----------------
__global__ __launch_bounds__(256) void scatter_kernel(const int* __restrict__ ei,
                                                      int* __restrict__ cursor,
                                                      int* __restrict__ rowOf) {
  int e = blockIdx.x * 256 + threadIdx.x;
  if (e < NE) {
    int c = ei[NE + e];
    int p = atomicAdd(&cursor[c], 1);
    rowOf[p] = ei[e];
  }
}

// ---------------- weight transposes ----------------
__global__ __launch_bounds__(256) void wt12_kernel(const float* __restrict__ w,
                                                   short* __restrict__ wt) {
  int i = blockIdx.x * 256 + threadIdx.x;  // over 3*256*128
  if (i >= 3 * 256 * DIM) return;
  int k = i % DIM, o = (i / DIM) % 256, s = i / (DIM * 256);
  int krow = (o < DIM) ? k : (DIM + k);
  int d = o & (DIM - 1);
  wt[i] = f2bf(w[((size_t)s * 259 + krow) * DIM + d]);
}
__global__ __launch_bounds__(256) void wt_upd_kernel(const float* __restrict__ w,
                                                     short* __restrict__ wt) {
  int i = blockIdx.x * 256 + threadIdx.x;  // over 3*128*256
  if (i >= 3 * DIM * KUPD) return;
  int k = i % KUPD, d = (i / KUPD) % DIM, s = i / (KUPD * DIM);
  wt[i] = f2bf(w[((size_t)s * KUPD + k) * DIM + d]);
}

// ---------------- P1/P2 GEMM: P12b[n][half*128+o] ----------------
// stage both halves' weights once; each wave does 4 node-tiles x 2 halves
__global__ __launch_bounds__(512) void p12_kernel(const short* __restrict__ hb,
                                                  const short* __restrict__ wt12_s,  // [256][128]
                                                  short* __restrict__ P12b) {
  __shared__ short wlds[256][136];  // 69.6 KB
  const int t = threadIdx.x;
  const int wid = t >> 6, lane = t & 63;
  const int m = lane & 15, kg = lane >> 4;
  for (int i = t * 8; i < 256 * DIM; i += 512 * 8) {
    int r = i >> 7, c = i & 127;
    *(bf16x8*)(&wlds[r][c]) = *(const bf16x8*)(wt12_s + i);
  }
  __syncthreads();
#pragma unroll
  for (int tile = 0; tile < 4; ++tile) {
    int tid = blockIdx.x * 32 + wid * 4 + tile;
    if (tid >= NN / 16) break;
    int nbase = tid * 16;
    const short* hrow = hb + (size_t)(nbase + m) * DIM;
    bf16x8 bfrag[4];
#pragma unroll
    for (int cc = 0; cc < 4; ++cc)
      bfrag[cc] = *(const bf16x8*)(hrow + cc * 32 + kg * 8);
#pragma unroll
    for (int half = 0; half < 2; ++half) {
      f32x4 acc[8];
#pragma unroll
      for (int i = 0; i < 8; ++i) acc[i] = (f32x4)0.0f;
#pragma unroll
      for (int cc = 0; cc < 4; ++cc) {
#pragma unroll
        for (int tl = 0; tl < 8; ++tl) {
          bf16x8 afrag = *(const bf16x8*)(&wlds[half * DIM + tl * 16 + m][cc * 32 + kg * 8]);
          acc[tl] = __builtin_amdgcn_mfma_f32_16x16x32_bf16(afrag, bfrag[cc], acc[tl], 0, 0, 0);
        }
      }
#pragma unroll
      for (int tl = 0; tl < 8; ++tl) {
        bf16x4 p;
#pragma unroll
        for (int j = 0; j < 4; ++j) p[j] = f2bf(acc[tl][j]);
        *(bf16x4*)(P12b + (size_t)(nbase + m) * 256 + half * DIM + tl * 16 + kg * 4) = p;
      }
    }
  }
}

// ---------------- message + aggregate: one wave per destination node ----------------
// half-wave split: lanes 0-31 process edge j (4 dims/lane), lanes 32-63 edge j+1
__global__ __launch_bounds__(512) void msg_agg_kernel(
    const short* __restrict__ P12b, const float* __restrict__ pos,
    const int* __restrict__ rowOf, const int* __restrict__ off,
    const float* __restrict__ wmsg_s,  // msg_w + s*259*128 (f32)
    const float* __restrict__ bias_s, float* __restrict__ agg) {
  const int t = threadIdx.x;
  const int wid = t >> 6, lane = t & 63;
  const int n = blockIdx.x * 8 + wid;  // grid covers exactly NN
  const int half = lane >> 5;
  const int d0 = (lane & 31) * 4;
  const float4 w30 = *(const float4*)(wmsg_s + 256 * DIM + d0);
  const float4 w31 = *(const float4*)(wmsg_s + 257 * DIM + d0);
  const float4 w32 = *(const float4*)(wmsg_s + 258 * DIM + d0);
  const float4 bi = *(const float4*)(bias_s + d0);
  bf16x4 p2v = *(const bf16x4*)(P12b + (size_t)n * 256 + DIM + d0);
  const float pb0 = bf2f((unsigned short)p2v[0]) + bi.x;
  const float pb1 = bf2f((unsigned short)p2v[1]) + bi.y;
  const float pb2 = bf2f((unsigned short)p2v[2]) + bi.z;
  const float pb3 = bf2f((unsigned short)p2v[3]) + bi.w;
  const float pc0 = pos[3 * n], pc1 = pos[3 * n + 1], pc2 = pos[3 * n + 2];
  const int start = off[n], end = off[n + 1];
  float a0 = 0.f, a1 = 0.f, a2 = 0.f, a3 = 0.f;
  for (int base = start; base < end; base += 64) {
    int mcnt = end - base;
    if (mcnt > 64) mcnt = 64;
    int r_l = (lane < mcnt) ? rowOf[base + lane] : 0;
    for (int j = 0; j < mcnt; j += 2) {
      int row = __shfl(r_l, j + half, 64);
      bf16x4 p1v = *(const bf16x4*)(P12b + (size_t)row * 256 + d0);
      float e0 = pos[3 * row] - pc0;
      float e1 = pos[3 * row + 1] - pc1;
      float e2 = pos[3 * row + 2] - pc2;
      float v0 = bf2f((unsigned short)p1v[0]) + pb0 + e0 * w30.x + e1 * w31.x + e2 * w32.x;
      float v1 = bf2f((unsigned short)p1v[1]) + pb1 + e0 * w30.y + e1 * w31.y + e2 * w32.y;
      float v2 = bf2f((unsigned short)p1v[2]) + pb2 + e0 * w30.z + e1 * w31.z + e2 * w32.z;
      float v3 = bf2f((unsigned short)p1v[3]) + pb3 + e0 * w30.w + e1 * w31.w + e2 * w32.w;
      float g0 = fgelu(v0), g1 = fgelu(v1), g2 = fgelu(v2), g3 = fgelu(v3);
      float s1 = (g0 + g1) + (g2 + g3);
      float s2 = (g0 * g0 + g1 * g1) + (g2 * g2 + g3 * g3);
#pragma unroll
      for (int mask = 1; mask < 32; mask <<= 1) {
        s1 += __shfl_xor(s1, mask, 64);
        s2 += __shfl_xor(s2, mask, 64);
      }
      float mean = s1 * (1.0f / 128.0f);
      float rstd = rsqrtf(s2 * (1.0f / 128.0f) - mean * mean + 1e-5f);
      // lanes in an inactive (odd-tail) upper half contribute 0
      float rs = (half == 0 || (j + 1) < mcnt) ? rstd : 0.0f;
      a0 += (g0 - mean) * rs;
      a1 += (g1 - mean) * rs;
      a2 += (g2 - mean) * rs;
      a3 += (g3 - mean) * rs;
    }
  }
  a0 += __shfl_xor(a0, 32, 64);
  a1 += __shfl_xor(a1, 32, 64);
  a2 += __shfl_xor(a2, 32, 64);
  a3 += __shfl_xor(a3, 32, 64);
  if (half == 0)
    *(float4*)(agg + (size_t)n * DIM + d0) = make_float4(a0, a1, a2, a3);
}

// ---------------- update kernel: stage [128][256] once; 4 tiles/wave ----------------
__global__ __launch_bounds__(512) void upd_kernel(
    const short* __restrict__ hb, const float* __restrict__ agg,
    const float* __restrict__ rden, const short* __restrict__ wt,  // [128][256]
    const float* __restrict__ bias, float* __restrict__ h, short* __restrict__ hbo) {
  __shared__ short wlds[DIM][264];  // 67.6 KB
  const int t = threadIdx.x;
  const int wid = t >> 6, lane = t & 63;
  const int m = lane & 15, kg = lane >> 4;
  for (int i = t * 8; i < DIM * 256; i += 512 * 8) {
    int r = i >> 8, c = i & 255;
    *(bf16x8*)(&wlds[r][c]) = *(const bf16x8*)(wt + i);
  }
  __syncthreads();
#pragma unroll
  for (int tile = 0; tile < 4; ++tile) {
    int tid = blockIdx.x * 32 + wid * 4 + tile;
    if (tid >= NN / 16) break;
    int nbase = tid * 16;
    const int nA = nbase + m;
    const short* hrow = hb + (size_t)nA * DIM;
    const float rd = rden[nA];

    f32x4 acc[8];
#pragma unroll
    for (int i = 0; i < 8; ++i) acc[i] = (f32x4)0.0f;
#pragma unroll
    for (int cc = 0; cc < 8; ++cc) {
      bf16x8 a;
      if (cc < 4) {
        a = *(const bf16x8*)(hrow + cc * 32 + kg * 8);
      } else {
        const float* ap = agg + (size_t)nA * DIM + (cc - 4) * 32 + kg * 8;
#pragma unroll
        for (int j = 0; j < 8; ++j) a[j] = f2bf(ap[j] * rd);
      }
#pragma unroll
      for (int tl = 0; tl < 8; ++tl) {
        bf16x8 bfr = *(const bf16x8*)(&wlds[tl * 16 + m][cc * 32 + kg * 8]);
        acc[tl] = __builtin_amdgcn_mfma_f32_16x16x32_bf16(a, bfr, acc[tl], 0, 0, 0);
      }
    }

    float s1[4] = {0.f, 0.f, 0.f, 0.f}, s2[4] = {0.f, 0.f, 0.f, 0.f};
#pragma unroll
    for (int tl = 0; tl < 8; ++tl) {
      float bd = bias[tl * 16 + m];
#pragma unroll
      for (int j = 0; j < 4; ++j) {
        float xv = acc[tl][j] + bd;
        acc[tl][j] = xv;
        s1[j] += xv;
        s2[j] += xv * xv;
      }
    }
#pragma unroll
    for (int mask = 1; mask < 16; mask <<= 1) {
#pragma unroll
      for (int j = 0; j < 4; ++j) {
        s1[j] += __shfl_xor(s1[j], mask, 64);
        s2[j] += __shfl_xor(s2[j], mask, 64);
      }
    }
#pragma unroll
    for (int j = 0; j < 4; ++j) {
      float mean = s1[j] * (1.0f / 128.0f);
      float var = s2[j] * (1.0f / 128.0f) - mean * mean;
      float rstd = rsqrtf(var + 1e-5f);
      int nw = nbase + kg * 4 + j;
#pragma unroll
      for (int tl = 0; tl < 8; ++tl) {
        int d = tl * 16 + m;
        float hv = h[(size_t)nw * DIM + d] + (acc[tl][j] - mean) * rstd;
        h[(size_t)nw * DIM + d] = hv;
        hbo[(size_t)nw * DIM + d] = f2bf(hv);
      }
    }
  }
}

extern "C" void kernel_launch(void* const* d_in, const int* in_sizes, int n_in,
                              void* d_out, int out_size, void* d_ws, size_t ws_size,
                              hipStream_t stream) {
  const float* x       = (const float*)d_in[0];
  const float* pos     = (const float*)d_in[1];
  const int* ei        = (const int*)d_in[2];
  const float* embed_w = (const float*)d_in[3];
  const float* embed_b = (const float*)d_in[4];
  const float* msg_w   = (const float*)d_in[5];
  const float* msg_b   = (const float*)d_in[6];
  const float* upd_w   = (const float*)d_in[7];
  const float* upd_b   = (const float*)d_in[8];
  float* h = (float*)d_out;

  char* ws = (char*)d_ws;
  size_t off_b = 0;
  short* hb    = (short*)(ws + off_b); off_b += (size_t)NN * DIM * 2;
  short* P12b  = (short*)(ws + off_b); off_b += (size_t)NN * 256 * 2;
  float* agg   = (float*)(ws + off_b); off_b += (size_t)NN * DIM * 4;
  float* rden  = (float*)(ws + off_b); off_b += (size_t)NN * 4;
  int*   cnt   = (int*)(ws + off_b);   off_b += (size_t)NN * 4;
  int*   offs  = (int*)(ws + off_b);   off_b += (size_t)(NN + 16) * 4;
  int*   cursor= (int*)(ws + off_b);   off_b += (size_t)NN * 4;
  int*   rowOf = (int*)(ws + off_b);   off_b += (size_t)NE * 4;
  short* wt12  = (short*)(ws + off_b); off_b += (size_t)3 * 256 * DIM * 2;
  short* wtu   = (short*)(ws + off_b); off_b += (size_t)3 * DIM * KUPD * 2;

  hipMemsetAsync(cnt, 0, (size_t)NN * 4, stream);
  counts_kernel<<<(NE + 255) / 256, 256, 0, stream>>>(ei, cnt);
  scan_kernel<<<1, 1024, 0, stream>>>(cnt, offs, cursor, rden);
  scatter_kernel<<<(NE + 255) / 256, 256, 0, stream>>>(ei, cursor, rowOf);
  wt12_kernel<<<(3 * 256 * DIM + 255) / 256, 256, 0, stream>>>(msg_w, wt12);
  wt_upd_kernel<<<(3 * DIM * KUPD + 255) / 256, 256, 0, stream>>>(upd_w, wtu);
  embed_kernel<<<NN / 8, 256, 0, stream>>>(x, embed_w, embed_b, h, hb);

  for (int s = 0; s < 3; ++s) {
    p12_kernel<<<98, 512, 0, stream>>>(hb, wt12 + (size_t)s * 256 * DIM, P12b);
    msg_agg_kernel<<<NN / 8, 512, 0, stream>>>(P12b, pos, rowOf, offs,
                                               msg_w + (size_t)s * 259 * DIM,
                                               msg_b + (size_t)s * DIM, agg);
    upd_kernel<<<98, 512, 0, stream>>>(hb, agg, rden,
                                       wtu + (size_t)s * DIM * KUPD,
                                       upd_b + (size_t)s * DIM, h, hb);
  }
}

// Round 5
// 602.518 us; speedup vs baseline: 2.1156x; 1.2254x over previous
//
#include <hip/hip_runtime.h>
#include <hip/hip_bf16.h>

#define NN 50000
#define NE 800000
#define IND 64
#define DIM 128
#define KUPD 256
#define NB_SCAN 196  // ceil(NN/256)

typedef __attribute__((ext_vector_type(8))) short bf16x8;
typedef __attribute__((ext_vector_type(4))) short bf16x4;
typedef __attribute__((ext_vector_type(4))) float f32x4;

static __device__ __forceinline__ short f2bf(float f) {
  union { __hip_bfloat16 b; short s; } u;
  u.b = __float2bfloat16(f);
  return u.s;
}
static __device__ __forceinline__ float bf2f(unsigned short u) {
  union { float f; unsigned int i; } x; x.i = ((unsigned int)u) << 16; return x.f;
}
// tanh-form gelu: x * sigmoid(1.59576912*x*(1+0.044715*x^2)); max err ~3e-3
static __device__ __forceinline__ float fgelu(float x) {
  float u = x * x;
  float z = x * (1.59576912f + 0.0713548163f * u);
  float t = __expf(-z);
  return x / (1.0f + t);
}

// ---------------- embed: h = x @ W + b ; also bf16 mirror ----------------
__global__ __launch_bounds__(256) void embed_kernel(
    const float* __restrict__ x, const float* __restrict__ w,
    const float* __restrict__ b, float* __restrict__ h, short* __restrict__ hb) {
  __shared__ float ws[IND * DIM];   // 32 KB
  __shared__ float xs[8 * IND];     // 2 KB
  const int t = threadIdx.x;
  for (int i = t * 4; i < IND * DIM; i += 1024)
    *(float4*)(ws + i) = *(const float4*)(w + i);
  {
    int i = t * 4;
    if (i < 8 * IND)
      *(float4*)(xs + i) = *(const float4*)(x + (size_t)blockIdx.x * (8 * IND) + i);
  }
  __syncthreads();
  const int d = t & 127, g = t >> 7;
  const float bd = b[d];
  for (int nnod = g; nnod < 8; nnod += 2) {
    float acc = bd;
#pragma unroll
    for (int k = 0; k < IND; ++k) acc += xs[nnod * IND + k] * ws[k * DIM + d];
    const size_t n = (size_t)blockIdx.x * 8 + nnod;
    h[n * DIM + d] = acc;
    hb[n * DIM + d] = f2bf(acc);
  }
}

// ---------------- degree counts (int) ----------------
__global__ __launch_bounds__(256) void counts_kernel(const int* __restrict__ ei,
                                                     int* __restrict__ cnt) {
  int e = blockIdx.x * 256 + threadIdx.x;
  if (e < NE) atomicAdd(&cnt[ei[NE + e]], 1);
}

// ---------------- 3-phase scan ----------------
__global__ __launch_bounds__(256) void bsum_kernel(const int* __restrict__ cnt,
                                                   int* __restrict__ bsum) {
  int idx = blockIdx.x * 256 + threadIdx.x;
  int c = (idx < NN) ? cnt[idx] : 0;
#pragma unroll
  for (int m = 1; m < 64; m <<= 1) c += __shfl_xor(c, m, 64);
  __shared__ int wsum[4];
  if ((threadIdx.x & 63) == 0) wsum[threadIdx.x >> 6] = c;
  __syncthreads();
  if (threadIdx.x == 0) bsum[blockIdx.x] = wsum[0] + wsum[1] + wsum[2] + wsum[3];
}

__global__ __launch_bounds__(256) void bscan_kernel(const int* __restrict__ bsum,
                                                    int* __restrict__ boff) {
  __shared__ int sh[256];
  int t = threadIdx.x;
  int v = (t < NB_SCAN) ? bsum[t] : 0;
  sh[t] = v;
  __syncthreads();
  for (int d = 1; d < 256; d <<= 1) {
    int u = (t >= d) ? sh[t - d] : 0;
    __syncthreads();
    sh[t] += u;
    __syncthreads();
  }
  if (t < NB_SCAN) boff[t] = sh[t] - v;  // exclusive
}

__global__ __launch_bounds__(256) void final_scan_kernel(
    const int* __restrict__ cnt, const int* __restrict__ boff,
    int* __restrict__ off, int* __restrict__ cursor, float* __restrict__ rden) {
  __shared__ int sh[256];
  int b = blockIdx.x, t = threadIdx.x;
  int idx = b * 256 + t;
  int c = (idx < NN) ? cnt[idx] : 0;
  sh[t] = c;
  __syncthreads();
  for (int d = 1; d < 256; d <<= 1) {
    int u = (t >= d) ? sh[t - d] : 0;
    __syncthreads();
    sh[t] += u;
    __syncthreads();
  }
  if (idx < NN) {
    int e = boff[b] + sh[t] - c;  // exclusive prefix
    off[idx] = e;
    cursor[idx] = e;
    rden[idx] = 1.0f / fmaxf((float)c, 1.0f);
  }
  if (b == 0 && t == 0) off[NN] = NE;
}

// ---------------- scatter edges into CSR buckets ----------------
__global__ __launch_bounds__(256) void scatter_kernel(const int* __restrict__ ei,
                                                      int* __restrict__ cursor,
                                                      int* __restrict__ rowOf) {
  int e = blockIdx.x * 256 + threadIdx.x;
  if (e < NE) {
    int c = ei[NE + e];
    int p = atomicAdd(&cursor[c], 1);
    rowOf[p] = ei[e];
  }
}

// ---------------- weight transposes ----------------
__global__ __launch_bounds__(256) void wt12_kernel(const float* __restrict__ w,
                                                   short* __restrict__ wt) {
  int i = blockIdx.x * 256 + threadIdx.x;  // over 3*256*128
  if (i >= 3 * 256 * DIM) return;
  int k = i % DIM, o = (i / DIM) % 256, s = i / (DIM * 256);
  int krow = (o < DIM) ? k : (DIM + k);
  int d = o & (DIM - 1);
  wt[i] = f2bf(w[((size_t)s * 259 + krow) * DIM + d]);
}
__global__ __launch_bounds__(256) void wt_upd_kernel(const float* __restrict__ w,
                                                     short* __restrict__ wt) {
  int i = blockIdx.x * 256 + threadIdx.x;  // over 3*128*256
  if (i >= 3 * DIM * KUPD) return;
  int k = i % KUPD, d = (i / KUPD) % DIM, s = i / (KUPD * DIM);
  wt[i] = f2bf(w[((size_t)s * KUPD + k) * DIM + d]);
}

// ---------------- P1/P2 GEMM: P12b[n][half*128+o] ----------------
__global__ __launch_bounds__(512) void p12_kernel(const short* __restrict__ hb,
                                                  const short* __restrict__ wt12_s,  // [256][128]
                                                  short* __restrict__ P12b) {
  __shared__ short wlds[256][136];  // 69.6 KB
  const int t = threadIdx.x;
  const int wid = t >> 6, lane = t & 63;
  const int m = lane & 15, kg = lane >> 4;
  for (int i = t * 8; i < 256 * DIM; i += 512 * 8) {
    int r = i >> 7, c = i & 127;
    *(bf16x8*)(&wlds[r][c]) = *(const bf16x8*)(wt12_s + i);
  }
  __syncthreads();
#pragma unroll
  for (int tile = 0; tile < 4; ++tile) {
    int tid = blockIdx.x * 32 + wid * 4 + tile;
    if (tid >= NN / 16) break;
    int nbase = tid * 16;
    const short* hrow = hb + (size_t)(nbase + m) * DIM;
    bf16x8 bfrag[4];
#pragma unroll
    for (int cc = 0; cc < 4; ++cc)
      bfrag[cc] = *(const bf16x8*)(hrow + cc * 32 + kg * 8);
#pragma unroll
    for (int half = 0; half < 2; ++half) {
      f32x4 acc[8];
#pragma unroll
      for (int i = 0; i < 8; ++i) acc[i] = (f32x4)0.0f;
#pragma unroll
      for (int cc = 0; cc < 4; ++cc) {
#pragma unroll
        for (int tl = 0; tl < 8; ++tl) {
          bf16x8 afrag = *(const bf16x8*)(&wlds[half * DIM + tl * 16 + m][cc * 32 + kg * 8]);
          acc[tl] = __builtin_amdgcn_mfma_f32_16x16x32_bf16(afrag, bfrag[cc], acc[tl], 0, 0, 0);
        }
      }
#pragma unroll
      for (int tl = 0; tl < 8; ++tl) {
        bf16x4 p;
#pragma unroll
        for (int j = 0; j < 4; ++j) p[j] = f2bf(acc[tl][j]);
        *(bf16x4*)(P12b + (size_t)(nbase + m) * 256 + half * DIM + tl * 16 + kg * 4) = p;
      }
    }
  }
}

// ---------------- message + aggregate: one wave per destination node ----------------
// quarter-wave split: quarter q (16 lanes) processes edge j+q; 8 dims/lane
__global__ __launch_bounds__(512) void msg_agg_kernel(
    const short* __restrict__ P12b, const float* __restrict__ pos,
    const int* __restrict__ rowOf, const int* __restrict__ off,
    const float* __restrict__ wmsg_s,  // msg_w + s*259*128 (f32)
    const float* __restrict__ bias_s, float* __restrict__ agg) {
  const int t = threadIdx.x;
  const int wid = t >> 6, lane = t & 63;
  const int n = blockIdx.x * 8 + wid;  // grid covers exactly NN
  const int q = lane >> 4;
  const int d0 = (lane & 15) * 8;
  float w30[8], w31[8], w32[8], pb[8];
  {
    *(float4*)(w30) = *(const float4*)(wmsg_s + 256 * DIM + d0);
    *(float4*)(w30 + 4) = *(const float4*)(wmsg_s + 256 * DIM + d0 + 4);
    *(float4*)(w31) = *(const float4*)(wmsg_s + 257 * DIM + d0);
    *(float4*)(w31 + 4) = *(const float4*)(wmsg_s + 257 * DIM + d0 + 4);
    *(float4*)(w32) = *(const float4*)(wmsg_s + 258 * DIM + d0);
    *(float4*)(w32 + 4) = *(const float4*)(wmsg_s + 258 * DIM + d0 + 4);
    bf16x8 p2v = *(const bf16x8*)(P12b + (size_t)n * 256 + DIM + d0);
#pragma unroll
    for (int k = 0; k < 8; ++k) pb[k] = bf2f((unsigned short)p2v[k]) + bias_s[d0 + k];
  }
  const float pc0 = pos[3 * n], pc1 = pos[3 * n + 1], pc2 = pos[3 * n + 2];
  const int start = off[n], end = off[n + 1];
  float a[8];
#pragma unroll
  for (int k = 0; k < 8; ++k) a[k] = 0.f;
  for (int base = start; base < end; base += 64) {
    int mcnt = end - base;
    if (mcnt > 64) mcnt = 64;
    int r_l = (lane < mcnt) ? rowOf[base + lane] : 0;
    for (int j = 0; j < mcnt; j += 4) {
      int jj = j + q;
      int row = __shfl(r_l, jj, 64);
      bf16x8 p1v = *(const bf16x8*)(P12b + (size_t)row * 256 + d0);
      float e0 = pos[3 * row] - pc0;
      float e1 = pos[3 * row + 1] - pc1;
      float e2 = pos[3 * row + 2] - pc2;
      float g[8];
      float s1 = 0.f, s2 = 0.f;
#pragma unroll
      for (int k = 0; k < 8; ++k) {
        float v = bf2f((unsigned short)p1v[k]) + pb[k] + e0 * w30[k] + e1 * w31[k] + e2 * w32[k];
        float gg = fgelu(v);
        g[k] = gg;
        s1 += gg;
        s2 += gg * gg;
      }
#pragma unroll
      for (int mask = 1; mask < 16; mask <<= 1) {
        s1 += __shfl_xor(s1, mask, 64);
        s2 += __shfl_xor(s2, mask, 64);
      }
      float mean = s1 * (1.0f / 128.0f);
      float rstd = rsqrtf(s2 * (1.0f / 128.0f) - mean * mean + 1e-5f);
      float rs = (jj < mcnt) ? rstd : 0.0f;
#pragma unroll
      for (int k = 0; k < 8; ++k) a[k] += (g[k] - mean) * rs;
    }
  }
#pragma unroll
  for (int k = 0; k < 8; ++k) {
    a[k] += __shfl_xor(a[k], 16, 64);
    a[k] += __shfl_xor(a[k], 32, 64);
  }
  if (q == 0) {
    *(float4*)(agg + (size_t)n * DIM + d0) = make_float4(a[0], a[1], a[2], a[3]);
    *(float4*)(agg + (size_t)n * DIM + d0 + 4) = make_float4(a[4], a[5], a[6], a[7]);
  }
}

// ---------------- update kernel: stage [128][256] once; 4 tiles/wave ----------------
__global__ __launch_bounds__(512) void upd_kernel(
    const short* __restrict__ hb, const float* __restrict__ agg,
    const float* __restrict__ rden, const short* __restrict__ wt,  // [128][256]
    const float* __restrict__ bias, float* __restrict__ h, short* __restrict__ hbo) {
  __shared__ short wlds[DIM][264];  // 67.6 KB
  const int t = threadIdx.x;
  const int wid = t >> 6, lane = t & 63;
  const int m = lane & 15, kg = lane >> 4;
  for (int i = t * 8; i < DIM * 256; i += 512 * 8) {
    int r = i >> 8, c = i & 255;
    *(bf16x8*)(&wlds[r][c]) = *(const bf16x8*)(wt + i);
  }
  __syncthreads();
#pragma unroll
  for (int tile = 0; tile < 4; ++tile) {
    int tid = blockIdx.x * 32 + wid * 4 + tile;
    if (tid >= NN / 16) break;
    int nbase = tid * 16;
    const int nA = nbase + m;
    const short* hrow = hb + (size_t)nA * DIM;
    const float rd = rden[nA];

    f32x4 acc[8];
#pragma unroll
    for (int i = 0; i < 8; ++i) acc[i] = (f32x4)0.0f;
#pragma unroll
    for (int cc = 0; cc < 8; ++cc) {
      bf16x8 a;
      if (cc < 4) {
        a = *(const bf16x8*)(hrow + cc * 32 + kg * 8);
      } else {
        const float* ap = agg + (size_t)nA * DIM + (cc - 4) * 32 + kg * 8;
#pragma unroll
        for (int j = 0; j < 8; ++j) a[j] = f2bf(ap[j] * rd);
      }
#pragma unroll
      for (int tl = 0; tl < 8; ++tl) {
        bf16x8 bfr = *(const bf16x8*)(&wlds[tl * 16 + m][cc * 32 + kg * 8]);
        acc[tl] = __builtin_amdgcn_mfma_f32_16x16x32_bf16(a, bfr, acc[tl], 0, 0, 0);
      }
    }

    float s1[4] = {0.f, 0.f, 0.f, 0.f}, s2[4] = {0.f, 0.f, 0.f, 0.f};
#pragma unroll
    for (int tl = 0; tl < 8; ++tl) {
      float bd = bias[tl * 16 + m];
#pragma unroll
      for (int j = 0; j < 4; ++j) {
        float xv = acc[tl][j] + bd;
        acc[tl][j] = xv;
        s1[j] += xv;
        s2[j] += xv * xv;
      }
    }
#pragma unroll
    for (int mask = 1; mask < 16; mask <<= 1) {
#pragma unroll
      for (int j = 0; j < 4; ++j) {
        s1[j] += __shfl_xor(s1[j], mask, 64);
        s2[j] += __shfl_xor(s2[j], mask, 64);
      }
    }
#pragma unroll
    for (int j = 0; j < 4; ++j) {
      float mean = s1[j] * (1.0f / 128.0f);
      float var = s2[j] * (1.0f / 128.0f) - mean * mean;
      float rstd = rsqrtf(var + 1e-5f);
      int nw = nbase + kg * 4 + j;
#pragma unroll
      for (int tl = 0; tl < 8; ++tl) {
        int d = tl * 16 + m;
        float hv = h[(size_t)nw * DIM + d] + (acc[tl][j] - mean) * rstd;
        h[(size_t)nw * DIM + d] = hv;
        hbo[(size_t)nw * DIM + d] = f2bf(hv);
      }
    }
  }
}

extern "C" void kernel_launch(void* const* d_in, const int* in_sizes, int n_in,
                              void* d_out, int out_size, void* d_ws, size_t ws_size,
                              hipStream_t stream) {
  const float* x       = (const float*)d_in[0];
  const float* pos     = (const float*)d_in[1];
  const int* ei        = (const int*)d_in[2];
  const float* embed_w = (const float*)d_in[3];
  const float* embed_b = (const float*)d_in[4];
  const float* msg_w   = (const float*)d_in[5];
  const float* msg_b   = (const float*)d_in[6];
  const float* upd_w   = (const float*)d_in[7];
  const float* upd_b   = (const float*)d_in[8];
  float* h = (float*)d_out;

  char* ws = (char*)d_ws;
  size_t off_b = 0;
  short* hb    = (short*)(ws + off_b); off_b += (size_t)NN * DIM * 2;
  short* P12b  = (short*)(ws + off_b); off_b += (size_t)NN * 256 * 2;
  float* agg   = (float*)(ws + off_b); off_b += (size_t)NN * DIM * 4;
  float* rden  = (float*)(ws + off_b); off_b += (size_t)NN * 4;
  int*   cnt   = (int*)(ws + off_b);   off_b += (size_t)NN * 4;
  int*   offs  = (int*)(ws + off_b);   off_b += (size_t)(NN + 16) * 4;
  int*   cursor= (int*)(ws + off_b);   off_b += (size_t)NN * 4;
  int*   rowOf = (int*)(ws + off_b);   off_b += (size_t)NE * 4;
  int*   bsum  = (int*)(ws + off_b);   off_b += (size_t)256 * 4;
  int*   boff  = (int*)(ws + off_b);   off_b += (size_t)256 * 4;
  short* wt12  = (short*)(ws + off_b); off_b += (size_t)3 * 256 * DIM * 2;
  short* wtu   = (short*)(ws + off_b); off_b += (size_t)3 * DIM * KUPD * 2;

  hipMemsetAsync(cnt, 0, (size_t)NN * 4, stream);
  counts_kernel<<<(NE + 255) / 256, 256, 0, stream>>>(ei, cnt);
  bsum_kernel<<<NB_SCAN, 256, 0, stream>>>(cnt, bsum);
  bscan_kernel<<<1, 256, 0, stream>>>(bsum, boff);
  final_scan_kernel<<<NB_SCAN, 256, 0, stream>>>(cnt, boff, offs, cursor, rden);
  scatter_kernel<<<(NE + 255) / 256, 256, 0, stream>>>(ei, cursor, rowOf);
  wt12_kernel<<<(3 * 256 * DIM + 255) / 256, 256, 0, stream>>>(msg_w, wt12);
  wt_upd_kernel<<<(3 * DIM * KUPD + 255) / 256, 256, 0, stream>>>(upd_w, wtu);
  embed_kernel<<<NN / 8, 256, 0, stream>>>(x, embed_w, embed_b, h, hb);

  for (int s = 0; s < 3; ++s) {
    p12_kernel<<<98, 512, 0, stream>>>(hb, wt12 + (size_t)s * 256 * DIM, P12b);
    msg_agg_kernel<<<NN / 8, 512, 0, stream>>>(P12b, pos, rowOf, offs,
                                               msg_w + (size_t)s * 259 * DIM,
                                               msg_b + (size_t)s * DIM, agg);
    upd_kernel<<<98, 512, 0, stream>>>(hb, agg, rden,
                                       wtu + (size_t)s * DIM * KUPD,
                                       upd_b + (size_t)s * DIM, h, hb);
  }
}